// Round 1
// baseline (192.956 us; speedup 1.0000x reference)
//
#include <hip/hip_runtime.h>

// Problem constants (fixed by the reference):
//   B=4096 batch, L=200 words, EMBEDDING_DIM=100, C=2 chunks of M=50, VOCAB=100000
constexpr int L_CONST = 200;
constexpr int C_ = 2;
constexpr int M_ = 50;
constexpr int ED = 100;      // embedding dim
constexpr float EPS = 1e-8f; // torch CosineSimilarity eps

// out[b] = sum_c ( sum_l alpha[l,c] * dot(ch[l,c,:], w_c) ) / ( sum_l alpha[l,c] )
// alpha  = exp( dot(ch, u_c) / (max(||ch||,eps) * max(||u_c||,eps)) )
__global__ __launch_bounds__(256, 4) void bc_kernel(
    const int*   __restrict__ idx,   // [B, L]
    const float* __restrict__ emb,   // [VOCAB, 100]
    const float* __restrict__ wgt,   // [100]  (weights, flattened [100,1])
    const float* __restrict__ att,   // [100]  (attend_u, flattened [2,50])
    float*       __restrict__ out,   // [B]
    int L)
{
    __shared__ float2 s_uw[ED];   // (attend_u[e], weights[e]) interleaved -> 1 ds_read_b64/elem
    __shared__ float  s_su[C_];   // 1 / max(||u_c||, eps)
    __shared__ float  s_red[4][4];

    const int t = threadIdx.x;
    const int b = blockIdx.x;

    if (t < ED) s_uw[t] = make_float2(att[t], wgt[t]);
    __syncthreads();
    if (t < C_) {
        float ss = 0.f;
        #pragma unroll
        for (int m = 0; m < M_; ++m) { float v = s_uw[t * M_ + m].x; ss += v * v; }
        s_su[t] = 1.0f / fmaxf(sqrtf(ss), EPS);
    }
    __syncthreads();

    float a0 = 0.f, a1 = 0.f, ap0 = 0.f, ap1 = 0.f;  // alpha_c, alpha_c*proj_c
    if (t < L) {
        const long long row = (long long)idx[(long long)b * L + t] * ED;
        const float4* p = reinterpret_cast<const float4*>(emb + row);  // 400B rows, 16B aligned
        float sq0 = 0.f, sq1 = 0.f, du0 = 0.f, du1 = 0.f, dw0 = 0.f, dw1 = 0.f;
        #pragma unroll
        for (int i = 0; i < ED / 4; ++i) {
            const float4 v = p[i];
            const float xs[4] = {v.x, v.y, v.z, v.w};
            #pragma unroll
            for (int k = 0; k < 4; ++k) {
                const int e = 4 * i + k;          // compile-time: chunk split resolved statically
                const float x = xs[k];
                const float2 uw = s_uw[e];        // broadcast (same addr all lanes) - conflict-free
                if (e < M_) { sq0 += x * x; du0 = fmaf(x, uw.x, du0); dw0 = fmaf(x, uw.y, dw0); }
                else        { sq1 += x * x; du1 = fmaf(x, uw.x, du1); dw1 = fmaf(x, uw.y, dw1); }
            }
        }
        const float c0 = du0 / fmaxf(sqrtf(sq0), EPS) * s_su[0];
        const float c1 = du1 / fmaxf(sqrtf(sq1), EPS) * s_su[1];
        a0  = __expf(c0);
        a1  = __expf(c1);
        ap0 = a0 * dw0;
        ap1 = a1 * dw1;
    }

    // Block reduction: 4 values across 256 threads (4 waves of 64)
    #pragma unroll
    for (int off = 32; off > 0; off >>= 1) {
        a0  += __shfl_down(a0,  off, 64);
        a1  += __shfl_down(a1,  off, 64);
        ap0 += __shfl_down(ap0, off, 64);
        ap1 += __shfl_down(ap1, off, 64);
    }
    const int wave = t >> 6;
    if ((t & 63) == 0) {
        s_red[wave][0] = a0;  s_red[wave][1] = a1;
        s_red[wave][2] = ap0; s_red[wave][3] = ap1;
    }
    __syncthreads();
    if (t == 0) {
        float A0 = 0.f, A1 = 0.f, P0 = 0.f, P1 = 0.f;
        #pragma unroll
        for (int wv = 0; wv < 4; ++wv) {
            A0 += s_red[wv][0]; A1 += s_red[wv][1];
            P0 += s_red[wv][2]; P1 += s_red[wv][3];
        }
        out[b] = P0 / A0 + P1 / A1;
    }
}

extern "C" void kernel_launch(void* const* d_in, const int* in_sizes, int n_in,
                              void* d_out, int out_size, void* d_ws, size_t ws_size,
                              hipStream_t stream) {
    const int*   idx = (const int*)d_in[0];    // word_idxs [4096,200] int32
    const float* emb = (const float*)d_in[1];  // emb_table [100000,100] f32
    const float* wgt = (const float*)d_in[2];  // weights   [100,1] f32
    const float* att = (const float*)d_in[3];  // attend_u  [2,50] f32
    float* out = (float*)d_out;                // [4096] f32

    const int B = out_size;                     // 4096
    const int L = in_sizes[0] / B;              // 200
    bc_kernel<<<B, 256, 0, stream>>>(idx, emb, wgt, att, out, L);
}

// Round 2
// 102.054 us; speedup vs baseline: 1.8907x; 1.8907x over previous
//
#include <hip/hip_runtime.h>

// Problem constants (fixed by the reference):
//   B=4096, L=200, EMBEDDING_DIM=100, C=2 chunks of M=50, VOCAB=100000
constexpr int C_ = 2;
constexpr int M_ = 50;
constexpr int ED = 100;
constexpr float EPS = 1e-8f;

// ---------------------------------------------------------------------------
// Pass 1: per-vocab-row statistics. alpha_c and alpha_c*proj_c depend ONLY on
// the row (u, w are constants), so precompute them once per vocab entry:
//   tbl[r] = (a0, a1, a0*dw0, a1*dw1)   -- 16 B/row, 1.6 MB total (fits L2)
// ---------------------------------------------------------------------------
__global__ __launch_bounds__(256, 4) void row_stats_kernel(
    const float* __restrict__ emb,   // [VOCAB, 100]
    const float* __restrict__ wgt,   // [100]
    const float* __restrict__ att,   // [100] = [2,50]
    float4*      __restrict__ tbl,   // [VOCAB]
    int vocab)
{
    __shared__ float2 s_uw[ED];   // (attend_u[e], weights[e])
    __shared__ float  s_su[C_];   // 1 / max(||u_c||, eps)

    const int t = threadIdx.x;
    if (t < ED) s_uw[t] = make_float2(att[t], wgt[t]);
    __syncthreads();
    if (t < C_) {
        float ss = 0.f;
        #pragma unroll
        for (int m = 0; m < M_; ++m) { float v = s_uw[t * M_ + m].x; ss += v * v; }
        s_su[t] = 1.0f / fmaxf(sqrtf(ss), EPS);
    }
    __syncthreads();

    const int r = blockIdx.x * 256 + t;
    if (r >= vocab) return;

    // 25 x float4 per row; a wave's working set is 64*400B = 25.6 KB < 32 KB L1,
    // so the strided-lane pattern is L1-absorbed and HBM sees one sequential pass.
    const float4* p = reinterpret_cast<const float4*>(emb + (long long)r * ED);
    float sq0 = 0.f, sq1 = 0.f, du0 = 0.f, du1 = 0.f, dw0 = 0.f, dw1 = 0.f;
    #pragma unroll
    for (int i = 0; i < ED / 4; ++i) {
        const float4 v = p[i];
        const float xs[4] = {v.x, v.y, v.z, v.w};
        #pragma unroll
        for (int k = 0; k < 4; ++k) {
            const int e = 4 * i + k;          // chunk split resolved at compile time
            const float x = xs[k];
            const float2 uw = s_uw[e];        // broadcast read, conflict-free
            if (e < M_) { sq0 += x * x; du0 = fmaf(x, uw.x, du0); dw0 = fmaf(x, uw.y, dw0); }
            else        { sq1 += x * x; du1 = fmaf(x, uw.x, du1); dw1 = fmaf(x, uw.y, dw1); }
        }
    }
    const float c0 = du0 / fmaxf(sqrtf(sq0), EPS) * s_su[0];
    const float c1 = du1 / fmaxf(sqrtf(sq1), EPS) * s_su[1];
    const float a0 = __expf(c0);
    const float a1 = __expf(c1);
    tbl[r] = make_float4(a0, a1, a0 * dw0, a1 * dw1);
}

// ---------------------------------------------------------------------------
// Pass 2: out[b] = sum_l ap0[idx] / sum_l a0[idx] + sum_l ap1[idx] / sum_l a1[idx]
// Gather is 16 B/row from the 1.6 MB table -> L2-resident.
// ---------------------------------------------------------------------------
__global__ __launch_bounds__(256, 4) void attend_kernel(
    const int*    __restrict__ idx,  // [B, L]
    const float4* __restrict__ tbl,  // [VOCAB]
    float*        __restrict__ out,  // [B]
    int L)
{
    __shared__ float s_red[4][4];
    const int t = threadIdx.x;
    const int b = blockIdx.x;

    float a0 = 0.f, a1 = 0.f, ap0 = 0.f, ap1 = 0.f;
    if (t < L) {
        const int r = idx[(long long)b * L + t];
        const float4 v = tbl[r];
        a0 = v.x; a1 = v.y; ap0 = v.z; ap1 = v.w;
    }

    #pragma unroll
    for (int off = 32; off > 0; off >>= 1) {
        a0  += __shfl_down(a0,  off, 64);
        a1  += __shfl_down(a1,  off, 64);
        ap0 += __shfl_down(ap0, off, 64);
        ap1 += __shfl_down(ap1, off, 64);
    }
    const int wave = t >> 6;
    if ((t & 63) == 0) {
        s_red[wave][0] = a0;  s_red[wave][1] = a1;
        s_red[wave][2] = ap0; s_red[wave][3] = ap1;
    }
    __syncthreads();
    if (t == 0) {
        float A0 = 0.f, A1 = 0.f, P0 = 0.f, P1 = 0.f;
        #pragma unroll
        for (int wv = 0; wv < 4; ++wv) {
            A0 += s_red[wv][0]; A1 += s_red[wv][1];
            P0 += s_red[wv][2]; P1 += s_red[wv][3];
        }
        out[b] = P0 / A0 + P1 / A1;
    }
}

extern "C" void kernel_launch(void* const* d_in, const int* in_sizes, int n_in,
                              void* d_out, int out_size, void* d_ws, size_t ws_size,
                              hipStream_t stream) {
    const int*   idx = (const int*)d_in[0];    // word_idxs [4096,200] int32
    const float* emb = (const float*)d_in[1];  // emb_table [100000,100] f32
    const float* wgt = (const float*)d_in[2];  // weights   [100,1] f32
    const float* att = (const float*)d_in[3];  // attend_u  [2,50] f32
    float* out = (float*)d_out;                // [4096] f32

    const int B     = out_size;                 // 4096
    const int L     = in_sizes[0] / B;          // 200
    const int vocab = in_sizes[1] / ED;         // 100000

    float4* tbl = (float4*)d_ws;                // 100000 * 16 B = 1.6 MB scratch

    row_stats_kernel<<<(vocab + 255) / 256, 256, 0, stream>>>(emb, wgt, att, tbl, vocab);
    attend_kernel<<<B, 256, 0, stream>>>(idx, tbl, out, L);
}